// Round 3
// baseline (5991.500 us; speedup 1.0000x reference)
//
#include <hip/hip_runtime.h>
#include <math.h>

#define LOG2E 1.4426950408889634f
#define LN2   0.6931471805599453f

typedef short    short8  __attribute__((ext_vector_type(8)));
typedef float    floatx4 __attribute__((ext_vector_type(4)));
typedef _Float16 half8   __attribute__((ext_vector_type(8)));

__constant__ int c_pi[28] = {0,0,0,0,0,0,0,1,1,1,1,1,1,2,2,2,2,2,3,3,3,3,4,4,4,5,5,6};
__constant__ int c_pj[28] = {1,2,3,4,5,6,7,2,3,4,5,6,7,3,4,5,6,7,4,5,6,7,5,6,7,6,7,7};

// ---------------- static device storage ----------------
__device__ unsigned short g_cellsL[16*256*256];   // bf16 bits, gathered local cells
__device__ unsigned short g_cellsG[8*512*256];    // bf16 bits, gathered global cells
__device__ float g_x2L[16*256];
__device__ float g_x2G[8*512];
__device__ int   g_idxL[16*256];
__device__ int   g_idxG[8*512];
// fp16 cost matrices, no transposes. Local: [0,56)=Cxy, [56,72)=Cxx. 9.4 MB
__device__ _Float16 g_CL[72*256*256];
// Global: [0,28)=Cxy, [28,36)=Cxx. 18.9 MB (total 28.3 MB)
__device__ _Float16 g_CG[36*512*512];
__device__ float g_fL[2][56*256];
__device__ float g_gL[2][56*256];
__device__ float g_pxL[2][16*256];
__device__ float g_fG[2][28*512];
__device__ float g_gG[2][28*512];
__device__ float g_pxG[2][8*512];
// column-LSE partials: locals 224 slices x 256, globals 448 slices x 512
__device__ float g_pm[286720];
__device__ float g_ps[286720];
__device__ int   g_cnt[84];                       // 56 local-pair + 28 global-pair

// ---------------- helpers ----------------
__device__ __forceinline__ unsigned short f2bf(float f) {
    unsigned u = __float_as_uint(f);
    u += 0x7fffu + ((u >> 16) & 1u);              // RNE; inputs are finite
    return (unsigned short)(u >> 16);
}
// agent(device)-scope coherent accesses: defeat stale per-XCD L2 lines
__device__ __forceinline__ void st_coh(float* p, float v) {
    __hip_atomic_store(p, v, __ATOMIC_RELAXED, __HIP_MEMORY_SCOPE_AGENT);
}
__device__ __forceinline__ float ld_coh(const float* p) {
    return __hip_atomic_load(p, __ATOMIC_RELAXED, __HIP_MEMORY_SCOPE_AGENT);
}

// ---------------- index lists: first-m matches in order (ballot scan) -------
__global__ void k_index(const int* __restrict__ labels, const int* __restrict__ subg) {
    int b = blockIdx.x, lane = threadIdx.x;       // 24 blocks x 64 threads
    int want_l, want_s, cap; int* out;
    if (b < 16) { want_l = b >> 3; want_s = b & 7; cap = 256; out = g_idxL + b*256; }
    else        { want_l = -1;     want_s = b - 16; cap = 512; out = g_idxG + (b-16)*512; }
    int cnt = 0;
    for (int base = 0; base < 4096; base += 64) {
        int i = base + lane;
        bool m = (subg[i] == want_s) && (want_l < 0 || labels[i] == want_l);
        unsigned long long mask = __ballot(m);
        int pos = cnt + __popcll(mask & ((1ull << lane) - 1ull));
        if (m && pos < cap) out[pos] = i;
        cnt += __popcll(mask);
    }
}

// ---------------- gather rows -> bf16 cells + fp32 sq-norms -----------------
__global__ void k_gather(const float* __restrict__ feat) {
    int wv = blockIdx.x*4 + (threadIdx.x >> 6);   // 8192 waves, one row each
    int lane = threadIdx.x & 63;
    const float* src; unsigned short* dst; float* x2out;
    if (wv < 4096) {
        int c = wv >> 8, row = wv & 255;
        src = feat + (size_t)g_idxL[c*256+row]*256;
        dst = g_cellsL + (size_t)(c*256+row)*256;
        x2out = g_x2L + c*256 + row;
    } else {
        int v = wv - 4096; int c = v >> 9, row = v & 511;
        src = feat + (size_t)g_idxG[c*512+row]*256;
        dst = g_cellsG + (size_t)(c*512+row)*256;
        x2out = g_x2G + c*512 + row;
    }
    floatx4 v4 = *(const floatx4*)(src + lane*4);
    float s = v4[0]*v4[0] + v4[1]*v4[1] + v4[2]*v4[2] + v4[3]*v4[3];
    unsigned lo = (unsigned)f2bf(v4[0]) | ((unsigned)f2bf(v4[1]) << 16);
    unsigned hi = (unsigned)f2bf(v4[2]) | ((unsigned)f2bf(v4[3]) << 16);
    unsigned* d32 = (unsigned*)dst;
    d32[lane*2] = lo; d32[lane*2+1] = hi;
    for (int o = 32; o; o >>= 1) s += __shfl_xor(s, o);
    if (lane == 0) *x2out = s;
}

// ---------------- cost matrices via bf16 MFMA (wave = one 16x16 tile) -------
__global__ void k_gemm() {
    int job = blockIdx.x*4 + (threadIdx.x >> 6);
    int lane = threadIdx.x & 63;
    const unsigned short *A, *B; _Float16* Cout; const float *x2a, *x2b;
    int m, ti, tj;
    if (job < 18432) {                            // local: 72 matrices x 256 tiles
        int mm = job >> 8, t = job & 255; ti = t >> 4; tj = t & 15; m = 256;
        int ca, cb;
        if (mm < 56) { int lbl = mm/28, q = mm%28; ca = lbl*8 + c_pi[q]; cb = lbl*8 + c_pj[q]; }
        else         { int c = mm-56; ca = cb = c; }
        A = g_cellsL + (size_t)ca*65536; B = g_cellsL + (size_t)cb*65536;
        x2a = g_x2L + ca*256; x2b = g_x2L + cb*256;
        Cout = g_CL + (size_t)mm*65536;
    } else {                                      // global: 36 matrices x 1024 tiles
        int jj = job - 18432; int mm = jj >> 10, t = jj & 1023; ti = t >> 5; tj = t & 31; m = 512;
        int ca, cb;
        if (mm < 28) { ca = c_pi[mm]; cb = c_pj[mm]; }
        else         { ca = cb = mm-28; }
        A = g_cellsG + (size_t)ca*131072; B = g_cellsG + (size_t)cb*131072;
        x2a = g_x2G + ca*512; x2b = g_x2G + cb*512;
        Cout = g_CG + (size_t)mm*262144;
    }
    int r = lane & 15, quad = lane >> 4;
    const unsigned short* Ap = A + (size_t)(ti*16 + r)*256 + quad*8;
    const unsigned short* Bp = B + (size_t)(tj*16 + r)*256 + quad*8;
    floatx4 acc = {0.f, 0.f, 0.f, 0.f};
    #pragma unroll
    for (int k = 0; k < 256; k += 32) {
        short8 av = *(const short8*)(Ap + k);
        short8 bv = *(const short8*)(Bp + k);
        acc = __builtin_amdgcn_mfma_f32_16x16x32_bf16(av, bv, acc, 0, 0, 0);
    }
    int jc = tj*16 + r;                           // D: col = lane&15, row = quad*4 + reg
    float y2 = x2b[jc];
    #pragma unroll
    for (int rr = 0; rr < 4; rr++) {
        int ir = ti*16 + quad*4 + rr;
        float v = x2a[ir] + y2 - 2.f*acc[rr];
        Cout[(size_t)ir*m + jc] = (_Float16)(0.5f*fmaxf(v, 0.f));
    }
}

// ---------------- zero the parity-0 potential buffers + counters ------------
__global__ void k_init() {
    int t = blockIdx.x*256 + threadIdx.x;         // 65536 threads
    if      (t < 14336) g_fL[0][t] = 0.f;
    else if (t < 28672) g_gL[0][t-14336] = 0.f;
    else if (t < 32768) g_pxL[0][t-28672] = 0.f;
    else if (t < 47104) g_fG[0][t-32768] = 0.f;
    else if (t < 61440) g_gG[0][t-47104] = 0.f;
    else                g_pxG[0][t-61440] = 0.f;
    if (blockIdx.x == 0 && threadIdx.x < 84) g_cnt[threadIdx.x] = 0;
}

// ---------------- row softmin pass (Cxx path, unchanged) --------------------
template<int M>
__device__ __forceinline__ void sm_pass(const _Float16* __restrict__ C,
    const float* __restrict__ hsrc, const float* __restrict__ fold,
    float* __restrict__ fout, int r0, float eps, float inv_eps, float loga,
    int hard, int fin)
{
    const int W = (M == 256) ? 16 : 32;
    int tid = threadIdx.x, lane = tid & 63, w = tid >> 6;
    int co = (M == 256) ? (lane & 31) : lane;
    float h[8];
    floatx4 h0 = *(const floatx4*)(hsrc + co*8);
    floatx4 h1 = *(const floatx4*)(hsrc + co*8 + 4);
    #pragma unroll
    for (int k = 0; k < 4; k++) { h[k] = loga + h0[k]*inv_eps; h[4+k] = loga + h1[k]*inv_eps; }
    int rbase = (M == 256) ? (r0 + w*16) : (r0 + w*8);
    int rowst = (M == 256) ? 2 : 1;
    int radd  = (M == 256) ? (lane >> 5) : 0;
    bool wr   = (M == 256) ? ((lane & 31) == 0) : (lane == 0);

    const _Float16* cp = C + (size_t)(rbase + radd)*M + co*8;
    half8 cv = *(const half8*)cp;
    #pragma unroll
    for (int s = 0; s < 8; s++) {
        half8 cvn = cv;
        if (s < 7) cvn = *(const half8*)(cp + (size_t)rowst*M);
        float tv[8]; float mx = -3.4e38f;
        #pragma unroll
        for (int k = 0; k < 8; k++) {
            float t = h[k] - (float)cv[k]*inv_eps;
            tv[k] = t; mx = fmaxf(mx, t);
        }
        #pragma unroll
        for (int o = W; o; o >>= 1) mx = fmaxf(mx, __shfl_xor(mx, o));
        float ft;
        if (!hard) {
            float sum = 0.f;
            #pragma unroll
            for (int k = 0; k < 8; k++) sum += exp2f((tv[k] - mx)*LOG2E);
            #pragma unroll
            for (int o = W; o; o >>= 1) sum += __shfl_xor(sum, o);
            ft = -eps*(mx + LN2*__log2f(sum));
        } else {
            ft = -eps*mx;
        }
        if (wr) {
            int row = rbase + rowst*s + radd;
            fout[row] = fin ? ft : 0.5f*(fold[row] + ft);
        }
        cv = cvn; cp += (size_t)rowst*M;
    }
}

// ---------------- fused row+col softmin pass (single sweep over Cxy) --------
// Streams a row-slice once: completes f for its rows (row-LSE, log2 domain)
// and accumulates online column-LSE partials for g. Slices of one matrix are
// merged by the last-arriving block (atomic counter, no spin -> order-safe).
template<int M>
__device__ __forceinline__ void fused_pass(
    const _Float16* __restrict__ C,
    const float* __restrict__ gpo, const float* __restrict__ fpo,
    float* __restrict__ fpn, float* __restrict__ gpn,
    float* __restrict__ pmM, float* __restrict__ psM,
    int* __restrict__ cnt, int q, int nsl, int r0,
    float eps, float inv_eps, float loga, int hard, int fin,
    float (*s_m)[512], float (*s_s)[512], int* s_flag)
{
    const int W = (M == 256) ? 16 : 32;
    int tid = threadIdx.x, lane = tid & 63, w = tid >> 6;
    int co = (M == 256) ? (lane & 31) : lane;
    const float i2  = inv_eps * LOG2E;
    const float lg2 = loga * LOG2E;
    float h2[8];
    floatx4 h0 = *(const floatx4*)(gpo + co*8);
    floatx4 h1 = *(const floatx4*)(gpo + co*8 + 4);
    #pragma unroll
    for (int k = 0; k < 4; k++) { h2[k] = lg2 + h0[k]*i2; h2[4+k] = lg2 + h1[k]*i2; }
    int rbase = (M == 256) ? (r0 + w*16) : (r0 + w*8);
    int rowst = (M == 256) ? 2 : 1;
    int radd  = (M == 256) ? (lane >> 5) : 0;
    bool wr   = (M == 256) ? ((lane & 31) == 0) : (lane == 0);
    int rr0 = rbase + radd;
    const _Float16* cp = C + (size_t)rr0*M + co*8;
    half8 cv = *(const half8*)cp;                 // 2-stage pipeline
    float fr = fpo[rr0];
    float m2[8], ss[8];
    #pragma unroll
    for (int k = 0; k < 8; k++) { m2[k] = -3.4e38f; ss[k] = 0.f; }
    #pragma unroll
    for (int s = 0; s < 8; s++) {
        half8 cvn = cv; float frn = fr;
        if (s < 7) { cvn = *(const half8*)(cp + (size_t)rowst*M); frn = fpo[rr0 + rowst*(s+1)]; }
        float a2 = lg2 + fr*i2;
        float tv[8]; float mx = -3.4e38f;
        #pragma unroll
        for (int k = 0; k < 8; k++) {
            float d = (float)cv[k]*(-i2);         // shared: -C/eps in log2 units
            tv[k] = h2[k] + d; mx = fmaxf(mx, tv[k]);
            float u = a2 + d;                     // column contribution
            float mn = fmaxf(m2[k], u);
            if (!hard) ss[k] = ss[k]*exp2f(m2[k]-mn) + exp2f(u-mn);
            m2[k] = mn;
        }
        #pragma unroll
        for (int o = W; o; o >>= 1) mx = fmaxf(mx, __shfl_xor(mx, o));
        float ft;
        if (!hard) {
            float sum = 0.f;
            #pragma unroll
            for (int k = 0; k < 8; k++) sum += exp2f(tv[k] - mx);
            #pragma unroll
            for (int o = W; o; o >>= 1) sum += __shfl_xor(sum, o);
            ft = -eps*LN2*(mx + __log2f(sum));
        } else {
            ft = -eps*LN2*mx;
        }
        if (wr) fpn[rr0 + rowst*s] = fin ? ft : 0.5f*(fr + ft);
        cv = cvn; fr = frn; cp += (size_t)rowst*M;
    }
    // ---- col-state merge: halves (M=256), then 4 waves via LDS ----
    if (M == 256) {
        #pragma unroll
        for (int k = 0; k < 8; k++) {
            float mo = __shfl_xor(m2[k], 32), so = __shfl_xor(ss[k], 32);
            float mn = fmaxf(m2[k], mo);
            if (!hard) ss[k] = ss[k]*exp2f(m2[k]-mn) + so*exp2f(mo-mn);
            m2[k] = mn;
        }
        if (lane < 32) {
            #pragma unroll
            for (int k = 0; k < 8; k++) { s_m[w][lane*8+k] = m2[k]; s_s[w][lane*8+k] = ss[k]; }
        }
    } else {
        #pragma unroll
        for (int k = 0; k < 8; k++) { s_m[w][lane*8+k] = m2[k]; s_s[w][lane*8+k] = ss[k]; }
    }
    __syncthreads();
    for (int c = tid; c < M; c += 256) {
        float m = s_m[0][c], s = s_s[0][c];
        #pragma unroll
        for (int ww = 1; ww < 4; ww++) {
            float mo = s_m[ww][c], so = s_s[ww][c];
            float mn = fmaxf(m, mo);
            if (!hard) s = s*exp2f(m-mn) + so*exp2f(mo-mn);
            m = mn;
        }
        st_coh(pmM + q*M + c, m);
        st_coh(psM + q*M + c, s);
    }
    __syncthreads();                              // barrier drains the stores (vmcnt 0)
    if (tid == 0) {
        __threadfence();
        int old = __hip_atomic_fetch_add(cnt, 1, __ATOMIC_ACQ_REL, __HIP_MEMORY_SCOPE_AGENT);
        *s_flag = (old == nsl - 1);
    }
    __syncthreads();
    if (*s_flag) {                                // last block finalizes g
        for (int c = tid; c < M; c += 256) {
            float m = ld_coh(pmM + c), s = ld_coh(psM + c);
            for (int qq = 1; qq < nsl; qq++) {
                float mo = ld_coh(pmM + qq*M + c), so = ld_coh(psM + qq*M + c);
                float mn = fmaxf(m, mo);
                if (!hard) s = s*exp2f(m-mn) + so*exp2f(mo-mn);
                m = mn;
            }
            float gt = hard ? (-eps*LN2*m) : (-eps*LN2*(m + __log2f(s)));
            gpn[c] = fin ? gt : 0.5f*(gpo[c] + gt);
        }
        if (tid == 0) __hip_atomic_store(cnt, 0, __ATOMIC_RELAXED, __HIP_MEMORY_SCOPE_AGENT);
    }
}

// ---------------- one eps-scaling iteration: 864 uniform 32KB blocks --------
//  b <224 : local pair p=b>>2, slice q=b&3 (64 rows), fused f+g
//  b <288 : local Cxx  c=(b-224)>>2, stripe (b-224)&3, row-only
//  b <736 : global pair p=(b-288)>>4, slice q=(b-288)&15 (32 rows), fused
//  else   : global Cxx c=(b-736)>>4, stripe (b-736)&15, row-only
__global__ void __launch_bounds__(256) k_iter(float eps, float inv_eps, int par, int hard, int fin) {
    const float LGA = -5.545177444479562f;        // -ln 256
    const float LGG = -6.238324625039508f;        // -ln 512
    __shared__ float s_m[4][512], s_s[4][512];
    __shared__ int s_flag;
    int b = blockIdx.x, po = par, pn = par ^ 1;
    if (b < 224) {
        int p = b >> 2, q = b & 3;
        fused_pass<256>(g_CL + (size_t)p*65536, g_gL[po]+p*256, g_fL[po]+p*256,
                        g_fL[pn]+p*256, g_gL[pn]+p*256,
                        g_pm + p*1024, g_ps + p*1024, g_cnt + p, q, 4, q*64,
                        eps, inv_eps, LGA, hard, fin, s_m, s_s, &s_flag);
    } else if (b < 288) {
        int t = b - 224, c = t >> 2;
        const float* h = g_pxL[po] + c*256;
        sm_pass<256>(g_CL + (size_t)(56+c)*65536, h, h, g_pxL[pn]+c*256, (t&3)*64,
                     eps, inv_eps, LGA, hard, fin);
    } else if (b < 736) {
        int t = b - 288, p = t >> 4, q = t & 15;
        fused_pass<512>(g_CG + (size_t)p*262144, g_gG[po]+p*512, g_fG[po]+p*512,
                        g_fG[pn]+p*512, g_gG[pn]+p*512,
                        g_pm + 57344 + p*8192, g_ps + 57344 + p*8192, g_cnt + 56 + p,
                        q, 16, q*32, eps, inv_eps, LGG, hard, fin, s_m, s_s, &s_flag);
    } else {
        int t = b - 736, c = t >> 4;
        const float* h = g_pxG[po] + c*512;
        sm_pass<512>(g_CG + (size_t)(28+c)*262144, h, h, g_pxG[pn]+c*512, (t&15)*32,
                     eps, inv_eps, LGG, hard, fin);
    }
}

// ---------------- final reduction to the scalar loss ------------------------
__global__ void k_combine(float* __restrict__ out) {
    __shared__ float red[4][4];
    int tid = threadIdx.x;                        // 256 threads
    float sfg_l = 0.f, spx_l = 0.f, sfg_g = 0.f, spx_g = 0.f;
    for (int i = tid; i < 14336; i += 256) sfg_l += g_fL[1][i] + g_gL[1][i];
    for (int i = tid; i < 4096;  i += 256) spx_l += g_pxL[1][i];
    for (int i = tid; i < 14336; i += 256) sfg_g += g_fG[1][i] + g_gG[1][i];
    for (int i = tid; i < 4096;  i += 256) spx_g += g_pxG[1][i];
    for (int o = 32; o; o >>= 1) {
        sfg_l += __shfl_xor(sfg_l, o); spx_l += __shfl_xor(spx_l, o);
        sfg_g += __shfl_xor(sfg_g, o); spx_g += __shfl_xor(spx_g, o);
    }
    int w = tid >> 6;
    if ((tid & 63) == 0) { red[0][w] = sfg_l; red[1][w] = spx_l; red[2][w] = sfg_g; red[3][w] = spx_g; }
    __syncthreads();
    if (tid == 0) {
        float SL = red[0][0]+red[0][1]+red[0][2]+red[0][3];
        float PL = red[1][0]+red[1][1]+red[1][2]+red[1][3];
        float SG = red[2][0]+red[2][1]+red[2][2]+red[2][3];
        float PG = red[3][0]+red[3][1]+red[3][2]+red[3][3];
        float local_l  = SL/14336.f - PL/2048.f;
        float global_l = SG/14336.f - PG/2048.f;
        out[0] = 1.0f*local_l + 0.5f*global_l;
    }
}

// ---------------- host launcher ---------------------------------------------
extern "C" void kernel_launch(void* const* d_in, const int* in_sizes, int n_in,
                              void* d_out, int out_size, void* d_ws, size_t ws_size,
                              hipStream_t stream) {
    (void)in_sizes; (void)n_in; (void)out_size; (void)d_ws; (void)ws_size;
    const float* feat  = (const float*)d_in[0];
    const int* labels  = (const int*)d_in[1];
    const int* subg    = (const int*)d_in[2];

    k_index <<<24,    64, 0, stream>>>(labels, subg);
    k_gather<<<2048, 256, 0, stream>>>(feat);
    k_gemm  <<<13824,256, 0, stream>>>();
    k_init  <<<256,  256, 0, stream>>>();

    // eps schedule identical to reference (double, like numpy)
    double eps0 = 4.0*256.0, ratio = 0.9*0.9, target = 1e-4*1e-4;
    int n = (int)ceil(log(target/eps0)/log(ratio));    // 121 -> 122 iterations
    float ef = 1e-8f;
    for (int k = 0; k <= n; k++) {
        double e = eps0 * pow(ratio, (double)k);
        if (e < target) e = target;
        ef = (float)e;
        int hard = (ef < 1e-5f) ? 1 : 0;
        k_iter<<<864, 256, 0, stream>>>(ef, (float)(1.0/(double)ef), k & 1, hard, 0);
    }
    // final extrapolation at eps_f (reads parity 0 carry, writes raw to parity 1)
    k_iter<<<864, 256, 0, stream>>>(ef, (float)(1.0/(double)ef), 0, 1, 1);
    k_combine<<<1, 256, 0, stream>>>((float*)d_out);
}

// Round 4
// 4376.429 us; speedup vs baseline: 1.3690x; 1.3690x over previous
//
#include <hip/hip_runtime.h>
#include <math.h>

#define LOG2E 1.4426950408889634f
#define LN2   0.6931471805599453f

typedef short    short8  __attribute__((ext_vector_type(8)));
typedef float    floatx4 __attribute__((ext_vector_type(4)));
typedef _Float16 half8   __attribute__((ext_vector_type(8)));

__constant__ int c_pi[28] = {0,0,0,0,0,0,0,1,1,1,1,1,1,2,2,2,2,2,3,3,3,3,4,4,4,5,5,6};
__constant__ int c_pj[28] = {1,2,3,4,5,6,7,2,3,4,5,6,7,3,4,5,6,7,4,5,6,7,5,6,7,6,7,7};

// ---------------- static device storage ----------------
__device__ unsigned short g_cellsL[16*256*256];   // bf16 bits, gathered local cells
__device__ unsigned short g_cellsG[8*512*256];    // bf16 bits, gathered global cells
__device__ float g_x2L[16*256];
__device__ float g_x2G[8*512];
__device__ int   g_idxL[16*256];
__device__ int   g_idxG[8*512];
// fp16 cost matrices, no transposes. Local: [0,56)=Cxy, [56,72)=Cxx. 9.4 MB
__device__ _Float16 g_CL[72*256*256];
// Global: [0,28)=Cxy, [28,36)=Cxx. 18.9 MB (total 28.3 MB)
__device__ _Float16 g_CG[36*512*512];
__device__ float g_fL[2][56*256];
__device__ float g_gL[2][56*256];
__device__ float g_pxL[2][16*256];
__device__ float g_fG[2][28*512];
__device__ float g_gG[2][28*512];
__device__ float g_pxG[2][8*512];
// column-LSE partials: local 56 x (2 slices x 256), global 28 x (4 slices x 512)
__device__ float g_pm[86016];
__device__ float g_ps[86016];

// ---------------- helpers ----------------
__device__ __forceinline__ unsigned short f2bf(float f) {
    unsigned u = __float_as_uint(f);
    u += 0x7fffu + ((u >> 16) & 1u);              // RNE; inputs are finite
    return (unsigned short)(u >> 16);
}

// ---------------- index lists: first-m matches in order (ballot scan) -------
__global__ void k_index(const int* __restrict__ labels, const int* __restrict__ subg) {
    int b = blockIdx.x, lane = threadIdx.x;       // 24 blocks x 64 threads
    int want_l, want_s, cap; int* out;
    if (b < 16) { want_l = b >> 3; want_s = b & 7; cap = 256; out = g_idxL + b*256; }
    else        { want_l = -1;     want_s = b - 16; cap = 512; out = g_idxG + (b-16)*512; }
    int cnt = 0;
    for (int base = 0; base < 4096; base += 64) {
        int i = base + lane;
        bool m = (subg[i] == want_s) && (want_l < 0 || labels[i] == want_l);
        unsigned long long mask = __ballot(m);
        int pos = cnt + __popcll(mask & ((1ull << lane) - 1ull));
        if (m && pos < cap) out[pos] = i;
        cnt += __popcll(mask);
    }
}

// ---------------- gather rows -> bf16 cells + fp32 sq-norms -----------------
__global__ void k_gather(const float* __restrict__ feat) {
    int wv = blockIdx.x*4 + (threadIdx.x >> 6);   // 8192 waves, one row each
    int lane = threadIdx.x & 63;
    const float* src; unsigned short* dst; float* x2out;
    if (wv < 4096) {
        int c = wv >> 8, row = wv & 255;
        src = feat + (size_t)g_idxL[c*256+row]*256;
        dst = g_cellsL + (size_t)(c*256+row)*256;
        x2out = g_x2L + c*256 + row;
    } else {
        int v = wv - 4096; int c = v >> 9, row = v & 511;
        src = feat + (size_t)g_idxG[c*512+row]*256;
        dst = g_cellsG + (size_t)(c*512+row)*256;
        x2out = g_x2G + c*512 + row;
    }
    floatx4 v4 = *(const floatx4*)(src + lane*4);
    float s = v4[0]*v4[0] + v4[1]*v4[1] + v4[2]*v4[2] + v4[3]*v4[3];
    unsigned lo = (unsigned)f2bf(v4[0]) | ((unsigned)f2bf(v4[1]) << 16);
    unsigned hi = (unsigned)f2bf(v4[2]) | ((unsigned)f2bf(v4[3]) << 16);
    unsigned* d32 = (unsigned*)dst;
    d32[lane*2] = lo; d32[lane*2+1] = hi;
    for (int o = 32; o; o >>= 1) s += __shfl_xor(s, o);
    if (lane == 0) *x2out = s;
}

// ---------------- cost matrices via bf16 MFMA (wave = one 16x16 tile) -------
__global__ void k_gemm() {
    int job = blockIdx.x*4 + (threadIdx.x >> 6);
    int lane = threadIdx.x & 63;
    const unsigned short *A, *B; _Float16* Cout; const float *x2a, *x2b;
    int m, ti, tj;
    if (job < 18432) {                            // local: 72 matrices x 256 tiles
        int mm = job >> 8, t = job & 255; ti = t >> 4; tj = t & 15; m = 256;
        int ca, cb;
        if (mm < 56) { int lbl = mm/28, q = mm%28; ca = lbl*8 + c_pi[q]; cb = lbl*8 + c_pj[q]; }
        else         { int c = mm-56; ca = cb = c; }
        A = g_cellsL + (size_t)ca*65536; B = g_cellsL + (size_t)cb*65536;
        x2a = g_x2L + ca*256; x2b = g_x2L + cb*256;
        Cout = g_CL + (size_t)mm*65536;
    } else {                                      // global: 36 matrices x 1024 tiles
        int jj = job - 18432; int mm = jj >> 10, t = jj & 1023; ti = t >> 5; tj = t & 31; m = 512;
        int ca, cb;
        if (mm < 28) { ca = c_pi[mm]; cb = c_pj[mm]; }
        else         { ca = cb = mm-28; }
        A = g_cellsG + (size_t)ca*131072; B = g_cellsG + (size_t)cb*131072;
        x2a = g_x2G + ca*512; x2b = g_x2G + cb*512;
        Cout = g_CG + (size_t)mm*262144;
    }
    int r = lane & 15, quad = lane >> 4;
    const unsigned short* Ap = A + (size_t)(ti*16 + r)*256 + quad*8;
    const unsigned short* Bp = B + (size_t)(tj*16 + r)*256 + quad*8;
    floatx4 acc = {0.f, 0.f, 0.f, 0.f};
    #pragma unroll
    for (int k = 0; k < 256; k += 32) {
        short8 av = *(const short8*)(Ap + k);
        short8 bv = *(const short8*)(Bp + k);
        acc = __builtin_amdgcn_mfma_f32_16x16x32_bf16(av, bv, acc, 0, 0, 0);
    }
    int jc = tj*16 + r;                           // D: col = lane&15, row = quad*4 + reg
    float y2 = x2b[jc];
    #pragma unroll
    for (int rr = 0; rr < 4; rr++) {
        int ir = ti*16 + quad*4 + rr;
        float v = x2a[ir] + y2 - 2.f*acc[rr];
        Cout[(size_t)ir*m + jc] = (_Float16)(0.5f*fmaxf(v, 0.f));
    }
}

// ---------------- zero parity-0 f/px and BOTH g parities --------------------
__global__ void k_init() {
    int t = blockIdx.x*256 + threadIdx.x;         // 95744 threads (374 blocks)
    if      (t < 14336) g_fL[0][t] = 0.f;
    else if (t < 28672) g_gL[0][t-14336] = 0.f;
    else if (t < 43008) g_gL[1][t-28672] = 0.f;
    else if (t < 47104) g_pxL[0][t-43008] = 0.f;
    else if (t < 61440) g_fG[0][t-47104] = 0.f;
    else if (t < 75776) g_gG[0][t-61440] = 0.f;
    else if (t < 90112) g_gG[1][t-75776] = 0.f;
    else if (t < 95744) g_pxG[0][t-90112] = 0.f;
}

// ---------------- row softmin pass (Cxx path), 128-row stripes --------------
template<int M>
__device__ __forceinline__ void sm_pass(const _Float16* __restrict__ C,
    const float* __restrict__ hsrc, const float* __restrict__ fold,
    float* __restrict__ fout, int r0, float eps, float inv_eps, float loga,
    int hard, int fin)
{
    const int W = (M == 256) ? 16 : 32;
    const int STEPS = (M == 256) ? 16 : 32;
    int tid = threadIdx.x, lane = tid & 63, w = tid >> 6;
    int co = (M == 256) ? (lane & 31) : lane;
    float h[8];
    floatx4 h0 = *(const floatx4*)(hsrc + co*8);
    floatx4 h1 = *(const floatx4*)(hsrc + co*8 + 4);
    #pragma unroll
    for (int k = 0; k < 4; k++) { h[k] = loga + h0[k]*inv_eps; h[4+k] = loga + h1[k]*inv_eps; }
    int rbase = r0 + w*32;
    int rowst = (M == 256) ? 2 : 1;
    int radd  = (M == 256) ? (lane >> 5) : 0;
    bool wr   = (M == 256) ? ((lane & 31) == 0) : (lane == 0);
    int rr0 = rbase + radd;
    const _Float16* cp = C + (size_t)rr0*M + co*8;
    half8 cv = *(const half8*)cp;                 // 2-stage pipeline
    #pragma unroll 4
    for (int s = 0; s < STEPS; s++) {
        half8 cvn = cv;
        if (s < STEPS-1) cvn = *(const half8*)(cp + (size_t)rowst*M);
        float tv[8]; float mx = -3.4e38f;
        #pragma unroll
        for (int k = 0; k < 8; k++) {
            float t = h[k] - (float)cv[k]*inv_eps;
            tv[k] = t; mx = fmaxf(mx, t);
        }
        #pragma unroll
        for (int o = W; o; o >>= 1) mx = fmaxf(mx, __shfl_xor(mx, o));
        float ft;
        if (!hard) {
            float sum = 0.f;
            #pragma unroll
            for (int k = 0; k < 8; k++) sum += exp2f((tv[k] - mx)*LOG2E);
            #pragma unroll
            for (int o = W; o; o >>= 1) sum += __shfl_xor(sum, o);
            ft = -eps*(mx + LN2*__log2f(sum));
        } else {
            ft = -eps*mx;                         // |err| <= eps*ln(M), negligible
        }
        if (wr) {
            int row = rr0 + rowst*s;
            fout[row] = fin ? ft : 0.5f*(fold[row] + ft);
        }
        cv = cvn; cp += (size_t)rowst*M;
    }
}

// ---------------- fused pass: combine(prev partials) + row f + col partials -
// Launch k: (1) combine launch k-1's column partials -> g_k (LDS; slice-0
// block persists it for launch k+1), (2) single sweep of a 128-row slice:
// row-LSE -> f_{k+1}, online column-LSE partials -> plain cached stores.
// Cross-launch visibility comes from the dispatch boundary (no fences).
template<int M>
__device__ __forceinline__ void fused_pass(
    const _Float16* __restrict__ C,
    float* __restrict__ pm, float* __restrict__ ps,
    const float* __restrict__ gpo, float* __restrict__ gpn,
    const float* __restrict__ fpo, float* __restrict__ fpn,
    int q, float eps, float inv_eps, float loga, int hard, int fin,
    float prev_eps, int prev_hard, int first,
    float* s_g, float (*s_m)[512], float (*s_s)[512])
{
    const int NSL = (M == 256) ? 2 : 4;
    const int STEPS = (M == 256) ? 16 : 32;
    const int W = (M == 256) ? 16 : 32;
    int tid = threadIdx.x, lane = tid & 63, w = tid >> 6;
    // ---- phase 1: finalize g_k from previous launch's partials ----
    if (first) {
        for (int c = tid; c < M; c += 256) s_g[c] = 0.f;
    } else {
        for (int c = tid; c < M; c += 256) {
            float m = pm[c];
            float s = prev_hard ? 0.f : ps[c];
            #pragma unroll
            for (int sl = 1; sl < NSL; sl++) {
                float mo = pm[sl*M + c];
                if (!prev_hard) {
                    float so = ps[sl*M + c];
                    float mn = fmaxf(m, mo);
                    s = s*exp2f(m - mn) + so*exp2f(mo - mn);
                    m = mn;
                } else m = fmaxf(m, mo);
            }
            float gt = prev_hard ? (-prev_eps*LN2*m)
                                 : (-prev_eps*LN2*(m + __log2f(s)));
            float gn = 0.5f*(gpo[c] + gt);
            s_g[c] = gn;
            if (q == 0) gpn[c] = gn;              // carry for next launch
        }
    }
    __syncthreads();
    // ---- phase 2: fused row+col sweep ----
    const float i2  = inv_eps * LOG2E;
    const float lg2 = loga * LOG2E;
    int co = (M == 256) ? (lane & 31) : lane;
    float h2[8];
    floatx4 h0 = *(const floatx4*)(s_g + co*8);
    floatx4 h1 = *(const floatx4*)(s_g + co*8 + 4);
    #pragma unroll
    for (int k = 0; k < 4; k++) { h2[k] = lg2 + h0[k]*i2; h2[4+k] = lg2 + h1[k]*i2; }
    int rbase = q*128 + w*32;
    int rowst = (M == 256) ? 2 : 1;
    int radd  = (M == 256) ? (lane >> 5) : 0;
    bool wr   = (M == 256) ? ((lane & 31) == 0) : (lane == 0);
    int rr0 = rbase + radd;
    const _Float16* cp = C + (size_t)rr0*M + co*8;
    half8 cv = *(const half8*)cp;                 // 2-stage pipeline
    float fr = fpo[rr0];
    float m2[8], ss[8];
    #pragma unroll
    for (int k = 0; k < 8; k++) { m2[k] = -3.4e38f; ss[k] = 0.f; }
    #pragma unroll 4
    for (int s = 0; s < STEPS; s++) {
        half8 cvn = cv; float frn = fr;
        if (s < STEPS-1) { cvn = *(const half8*)(cp + (size_t)rowst*M); frn = fpo[rr0 + rowst*(s+1)]; }
        float a2 = lg2 + fr*i2;
        float tv[8]; float mx = -3.4e38f;
        #pragma unroll
        for (int k = 0; k < 8; k++) {
            float d = (float)cv[k]*(-i2);         // shared: -C/eps in log2 units
            tv[k] = h2[k] + d; mx = fmaxf(mx, tv[k]);
            float u = a2 + d;                     // column contribution
            float mn = fmaxf(m2[k], u);
            if (!hard) ss[k] = ss[k]*exp2f(m2[k]-mn) + exp2f(u-mn);
            m2[k] = mn;
        }
        #pragma unroll
        for (int o = W; o; o >>= 1) mx = fmaxf(mx, __shfl_xor(mx, o));
        float ft;
        if (!hard) {
            float sum = 0.f;
            #pragma unroll
            for (int k = 0; k < 8; k++) sum += exp2f(tv[k] - mx);
            #pragma unroll
            for (int o = W; o; o >>= 1) sum += __shfl_xor(sum, o);
            ft = -eps*LN2*(mx + __log2f(sum));
        } else {
            ft = -eps*LN2*mx;
        }
        if (wr) fpn[rr0 + rowst*s] = fin ? ft : 0.5f*(fr + ft);
        cv = cvn; fr = frn; cp += (size_t)rowst*M;
    }
    // ---- phase 3: merge col states across waves, store this slice's partial
    if (M == 256) {                               // halves share columns
        #pragma unroll
        for (int k = 0; k < 8; k++) {
            float mo = __shfl_xor(m2[k], 32), so = __shfl_xor(ss[k], 32);
            float mn = fmaxf(m2[k], mo);
            if (!hard) ss[k] = ss[k]*exp2f(m2[k]-mn) + so*exp2f(mo-mn);
            m2[k] = mn;
        }
        if (lane < 32) {
            #pragma unroll
            for (int k = 0; k < 8; k++) {
                s_m[w][lane*8+k] = m2[k];
                if (!hard) s_s[w][lane*8+k] = ss[k];
            }
        }
    } else {
        #pragma unroll
        for (int k = 0; k < 8; k++) {
            s_m[w][lane*8+k] = m2[k];
            if (!hard) s_s[w][lane*8+k] = ss[k];
        }
    }
    __syncthreads();
    for (int c = tid; c < M; c += 256) {
        float m = s_m[0][c];
        float s = hard ? 0.f : s_s[0][c];
        #pragma unroll
        for (int ww = 1; ww < 4; ww++) {
            float mo = s_m[ww][c];
            if (!hard) {
                float so = s_s[ww][c];
                float mn = fmaxf(m, mo);
                s = s*exp2f(m-mn) + so*exp2f(mo-mn);
                m = mn;
            } else m = fmaxf(m, mo);
        }
        pm[q*M + c] = m;
        if (!hard) ps[q*M + c] = s;
    }
}

// ---------------- one eps-scaling iteration: 288 x 128-row blocks -----------
//  b <112 : global pair p=b>>2, slice q=b&3          (fused, 128 KB stream)
//  b <144 : global Cxx  c=(b-112)>>2, stripe (b-112)&3 (row-only)
//  b <256 : local pair p=(b-144)>>1, slice q=(b-144)&1 (fused, 64 KB stream)
//  else   : local Cxx  c=(b-256)>>1, stripe (b-256)&1  (row-only)
__global__ void __launch_bounds__(256) k_iter(float eps, float inv_eps, int par,
        int hard, int fin, int first, float prev_eps, int prev_hard) {
    const float LGA = -5.545177444479562f;        // -ln 256
    const float LGG = -6.238324625039508f;        // -ln 512
    __shared__ float s_g[512];
    __shared__ float s_m[4][512], s_s[4][512];
    int b = blockIdx.x, po = par, pn = par ^ 1;
    if (b < 112) {
        int p = b >> 2, q = b & 3;
        fused_pass<512>(g_CG + (size_t)p*262144,
            g_pm + 28672 + p*2048, g_ps + 28672 + p*2048,
            g_gG[po]+p*512, g_gG[pn]+p*512,
            g_fG[po]+p*512, g_fG[pn]+p*512,
            q, eps, inv_eps, LGG, hard, fin, prev_eps, prev_hard, first,
            s_g, s_m, s_s);
    } else if (b < 144) {
        int t = b - 112, c = t >> 2, q = t & 3;
        const float* h = g_pxG[po] + c*512;
        sm_pass<512>(g_CG + (size_t)(28+c)*262144, h, h, g_pxG[pn]+c*512, q*128,
                     eps, inv_eps, LGG, hard, fin);
    } else if (b < 256) {
        int t = b - 144, p = t >> 1, q = t & 1;
        fused_pass<256>(g_CL + (size_t)p*65536,
            g_pm + p*512, g_ps + p*512,
            g_gL[po]+p*256, g_gL[pn]+p*256,
            g_fL[po]+p*256, g_fL[pn]+p*256,
            q, eps, inv_eps, LGA, hard, fin, prev_eps, prev_hard, first,
            s_g, s_m, s_s);
    } else {
        int t = b - 256, c = t >> 1, q = t & 1;
        const float* h = g_pxL[po] + c*256;
        sm_pass<256>(g_CL + (size_t)(56+c)*65536, h, h, g_pxL[pn]+c*256, q*128,
                     eps, inv_eps, LGA, hard, fin);
    }
}

// ---------------- finalize g_fin from the fin launch's partials -------------
__global__ void k_fin(float eps_f) {
    int b = blockIdx.x, tid = threadIdx.x;        // 84 blocks x 256
    if (b < 28) {                                 // global pairs (NSL=4, M=512)
        const float* pm = g_pm + 28672 + b*2048;
        for (int c = tid; c < 512; c += 256) {
            float m = fmaxf(fmaxf(pm[c], pm[512+c]), fmaxf(pm[1024+c], pm[1536+c]));
            g_gG[1][b*512 + c] = -eps_f*LN2*m;
        }
    } else {                                      // local pairs (NSL=2, M=256)
        int p = b - 28;
        const float* pm = g_pm + p*512;
        int c = tid;
        float m = fmaxf(pm[c], pm[256+c]);
        g_gL[1][p*256 + c] = -eps_f*LN2*m;
    }
}

// ---------------- final reduction to the scalar loss ------------------------
__global__ void k_combine(float* __restrict__ out) {
    __shared__ float red[4][4];
    int tid = threadIdx.x;                        // 256 threads
    float sfg_l = 0.f, spx_l = 0.f, sfg_g = 0.f, spx_g = 0.f;
    for (int i = tid; i < 14336; i += 256) sfg_l += g_fL[1][i] + g_gL[1][i];
    for (int i = tid; i < 4096;  i += 256) spx_l += g_pxL[1][i];
    for (int i = tid; i < 14336; i += 256) sfg_g += g_fG[1][i] + g_gG[1][i];
    for (int i = tid; i < 4096;  i += 256) spx_g += g_pxG[1][i];
    for (int o = 32; o; o >>= 1) {
        sfg_l += __shfl_xor(sfg_l, o); spx_l += __shfl_xor(spx_l, o);
        sfg_g += __shfl_xor(sfg_g, o); spx_g += __shfl_xor(spx_g, o);
    }
    int w = tid >> 6;
    if ((tid & 63) == 0) { red[0][w] = sfg_l; red[1][w] = spx_l; red[2][w] = sfg_g; red[3][w] = spx_g; }
    __syncthreads();
    if (tid == 0) {
        float SL = red[0][0]+red[0][1]+red[0][2]+red[0][3];
        float PL = red[1][0]+red[1][1]+red[1][2]+red[1][3];
        float SG = red[2][0]+red[2][1]+red[2][2]+red[2][3];
        float PG = red[3][0]+red[3][1]+red[3][2]+red[3][3];
        float local_l  = SL/14336.f - PL/2048.f;
        float global_l = SG/14336.f - PG/2048.f;
        out[0] = 1.0f*local_l + 0.5f*global_l;
    }
}

// ---------------- host launcher ---------------------------------------------
extern "C" void kernel_launch(void* const* d_in, const int* in_sizes, int n_in,
                              void* d_out, int out_size, void* d_ws, size_t ws_size,
                              hipStream_t stream) {
    (void)in_sizes; (void)n_in; (void)out_size; (void)d_ws; (void)ws_size;
    const float* feat  = (const float*)d_in[0];
    const int* labels  = (const int*)d_in[1];
    const int* subg    = (const int*)d_in[2];

    k_index <<<24,    64, 0, stream>>>(labels, subg);
    k_gather<<<2048, 256, 0, stream>>>(feat);
    k_gemm  <<<13824,256, 0, stream>>>();
    k_init  <<<374,  256, 0, stream>>>();

    // eps schedule identical to reference (double, like numpy)
    double eps0 = 4.0*256.0, ratio = 0.9*0.9, target = 1e-4*1e-4;
    int n = (int)ceil(log(target/eps0)/log(ratio));    // 121 -> 122 iterations
    float ef = 1e-8f;
    float prev_ef = 0.f; int prev_hard = 0;
    for (int k = 0; k <= n; k++) {
        double e = eps0 * pow(ratio, (double)k);
        if (e < target) e = target;
        ef = (float)e;
        int hard = (ef < 1e-5f) ? 1 : 0;
        k_iter<<<288, 256, 0, stream>>>(ef, (float)(1.0/(double)ef), k & 1,
                                        hard, 0, (k == 0) ? 1 : 0, prev_ef, prev_hard);
        prev_ef = ef; prev_hard = hard;
    }
    // final extrapolation at eps_f: combine(partials_121)->g_122, raw f/px,
    // col partials with f_122; then k_fin combines them into g_fin.
    k_iter<<<288, 256, 0, stream>>>(ef, (float)(1.0/(double)ef), 0,
                                    1, 1, 0, prev_ef, prev_hard);
    k_fin<<<84, 256, 0, stream>>>(ef);
    k_combine<<<1, 256, 0, stream>>>((float*)d_out);
}

// Round 5
// 3859.098 us; speedup vs baseline: 1.5526x; 1.1341x over previous
//
#include <hip/hip_runtime.h>
#include <math.h>

#define LOG2E 1.4426950408889634f
#define LN2   0.6931471805599453f

typedef short    short8  __attribute__((ext_vector_type(8)));
typedef float    floatx4 __attribute__((ext_vector_type(4)));
typedef _Float16 half8   __attribute__((ext_vector_type(8)));

__constant__ int c_pi[28] = {0,0,0,0,0,0,0,1,1,1,1,1,1,2,2,2,2,2,3,3,3,3,4,4,4,5,5,6};
__constant__ int c_pj[28] = {1,2,3,4,5,6,7,2,3,4,5,6,7,3,4,5,6,7,4,5,6,7,5,6,7,6,7,7};

// ---------------- static device storage ----------------
__device__ unsigned short g_cellsL[16*256*256];   // bf16 bits, gathered local cells
__device__ unsigned short g_cellsG[8*512*256];    // bf16 bits, gathered global cells
__device__ float g_x2L[16*256];
__device__ float g_x2G[8*512];
__device__ int   g_idxL[16*256];
__device__ int   g_idxG[8*512];
// fp16 cost matrices, no transposes. Local: [0,56)=Cxy, [56,72)=Cxx. 9.4 MB
__device__ _Float16 g_CL[72*256*256];
// Global: [0,28)=Cxy, [28,36)=Cxx. 18.9 MB (total 28.3 MB)
__device__ _Float16 g_CG[36*512*512];
__device__ float g_fL[2][56*256];
__device__ float g_gL[2][56*256];
__device__ float g_pxL[2][16*256];
__device__ float g_fG[2][28*512];
__device__ float g_gG[2][28*512];
__device__ float g_pxG[2][8*512];
// column-LSE partials: local 56 x (4 slices x 256) = 57344, then
// global 28 x (8 slices x 512) = 114688
__device__ float g_pm[172032];
__device__ float g_ps[172032];

// ---------------- helpers ----------------
__device__ __forceinline__ unsigned short f2bf(float f) {
    unsigned u = __float_as_uint(f);
    u += 0x7fffu + ((u >> 16) & 1u);              // RNE; inputs are finite
    return (unsigned short)(u >> 16);
}

// ---------------- index lists: first-m matches in order (ballot scan) -------
__global__ void k_index(const int* __restrict__ labels, const int* __restrict__ subg) {
    int b = blockIdx.x, lane = threadIdx.x;       // 24 blocks x 64 threads
    int want_l, want_s, cap; int* out;
    if (b < 16) { want_l = b >> 3; want_s = b & 7; cap = 256; out = g_idxL + b*256; }
    else        { want_l = -1;     want_s = b - 16; cap = 512; out = g_idxG + (b-16)*512; }
    int cnt = 0;
    for (int base = 0; base < 4096; base += 64) {
        int i = base + lane;
        bool m = (subg[i] == want_s) && (want_l < 0 || labels[i] == want_l);
        unsigned long long mask = __ballot(m);
        int pos = cnt + __popcll(mask & ((1ull << lane) - 1ull));
        if (m && pos < cap) out[pos] = i;
        cnt += __popcll(mask);
    }
}

// ---------------- gather rows -> bf16 cells + fp32 sq-norms -----------------
__global__ void k_gather(const float* __restrict__ feat) {
    int wv = blockIdx.x*4 + (threadIdx.x >> 6);   // 8192 waves, one row each
    int lane = threadIdx.x & 63;
    const float* src; unsigned short* dst; float* x2out;
    if (wv < 4096) {
        int c = wv >> 8, row = wv & 255;
        src = feat + (size_t)g_idxL[c*256+row]*256;
        dst = g_cellsL + (size_t)(c*256+row)*256;
        x2out = g_x2L + c*256 + row;
    } else {
        int v = wv - 4096; int c = v >> 9, row = v & 511;
        src = feat + (size_t)g_idxG[c*512+row]*256;
        dst = g_cellsG + (size_t)(c*512+row)*256;
        x2out = g_x2G + c*512 + row;
    }
    floatx4 v4 = *(const floatx4*)(src + lane*4);
    float s = v4[0]*v4[0] + v4[1]*v4[1] + v4[2]*v4[2] + v4[3]*v4[3];
    unsigned lo = (unsigned)f2bf(v4[0]) | ((unsigned)f2bf(v4[1]) << 16);
    unsigned hi = (unsigned)f2bf(v4[2]) | ((unsigned)f2bf(v4[3]) << 16);
    unsigned* d32 = (unsigned*)dst;
    d32[lane*2] = lo; d32[lane*2+1] = hi;
    for (int o = 32; o; o >>= 1) s += __shfl_xor(s, o);
    if (lane == 0) *x2out = s;
}

// ---------------- cost matrices via bf16 MFMA (wave = one 16x16 tile) -------
__global__ void k_gemm() {
    int job = blockIdx.x*4 + (threadIdx.x >> 6);
    int lane = threadIdx.x & 63;
    const unsigned short *A, *B; _Float16* Cout; const float *x2a, *x2b;
    int m, ti, tj;
    if (job < 18432) {                            // local: 72 matrices x 256 tiles
        int mm = job >> 8, t = job & 255; ti = t >> 4; tj = t & 15; m = 256;
        int ca, cb;
        if (mm < 56) { int lbl = mm/28, q = mm%28; ca = lbl*8 + c_pi[q]; cb = lbl*8 + c_pj[q]; }
        else         { int c = mm-56; ca = cb = c; }
        A = g_cellsL + (size_t)ca*65536; B = g_cellsL + (size_t)cb*65536;
        x2a = g_x2L + ca*256; x2b = g_x2L + cb*256;
        Cout = g_CL + (size_t)mm*65536;
    } else {                                      // global: 36 matrices x 1024 tiles
        int jj = job - 18432; int mm = jj >> 10, t = jj & 1023; ti = t >> 5; tj = t & 31; m = 512;
        int ca, cb;
        if (mm < 28) { ca = c_pi[mm]; cb = c_pj[mm]; }
        else         { ca = cb = mm-28; }
        A = g_cellsG + (size_t)ca*131072; B = g_cellsG + (size_t)cb*131072;
        x2a = g_x2G + ca*512; x2b = g_x2G + cb*512;
        Cout = g_CG + (size_t)mm*262144;
    }
    int r = lane & 15, quad = lane >> 4;
    const unsigned short* Ap = A + (size_t)(ti*16 + r)*256 + quad*8;
    const unsigned short* Bp = B + (size_t)(tj*16 + r)*256 + quad*8;
    floatx4 acc = {0.f, 0.f, 0.f, 0.f};
    #pragma unroll
    for (int k = 0; k < 256; k += 32) {
        short8 av = *(const short8*)(Ap + k);
        short8 bv = *(const short8*)(Bp + k);
        acc = __builtin_amdgcn_mfma_f32_16x16x32_bf16(av, bv, acc, 0, 0, 0);
    }
    int jc = tj*16 + r;                           // D: col = lane&15, row = quad*4 + reg
    float y2 = x2b[jc];
    #pragma unroll
    for (int rr = 0; rr < 4; rr++) {
        int ir = ti*16 + quad*4 + rr;
        float v = x2a[ir] + y2 - 2.f*acc[rr];
        Cout[(size_t)ir*m + jc] = (_Float16)(0.5f*fmaxf(v, 0.f));
    }
}

// ---------------- zero parity-0 f/px and BOTH g parities --------------------
__global__ void k_init() {
    int t = blockIdx.x*256 + threadIdx.x;         // 95744 threads (374 blocks)
    if      (t < 14336) g_fL[0][t] = 0.f;
    else if (t < 28672) g_gL[0][t-14336] = 0.f;
    else if (t < 43008) g_gL[1][t-28672] = 0.f;
    else if (t < 47104) g_pxL[0][t-43008] = 0.f;
    else if (t < 61440) g_fG[0][t-47104] = 0.f;
    else if (t < 75776) g_gG[0][t-61440] = 0.f;
    else if (t < 90112) g_gG[1][t-75776] = 0.f;
    else if (t < 95744) g_pxG[0][t-90112] = 0.f;
}

// ---------------- row softmin pass (Cxx path), 64-row stripes ---------------
// 4-deep C prefetch; h and f_old preloaded upfront.
template<int M>
__device__ __forceinline__ void sm_pass(const _Float16* __restrict__ C,
    const float* __restrict__ hsrc, const float* __restrict__ fold,
    float* __restrict__ fout, int r0, float eps, float inv_eps, float loga,
    int hard, int fin)
{
    const int W = (M == 256) ? 16 : 32;
    const int STEPS = (M == 256) ? 8 : 16;
    int tid = threadIdx.x, lane = tid & 63, w = tid >> 6;
    int co = (M == 256) ? (lane & 31) : lane;
    float h[8];
    floatx4 h0 = *(const floatx4*)(hsrc + co*8);
    floatx4 h1 = *(const floatx4*)(hsrc + co*8 + 4);
    #pragma unroll
    for (int k = 0; k < 4; k++) { h[k] = loga + h0[k]*inv_eps; h[4+k] = loga + h1[k]*inv_eps; }
    int rbase = r0 + w*16;
    int rowst = (M == 256) ? 2 : 1;
    int radd  = (M == 256) ? (lane >> 5) : 0;
    bool wr   = (M == 256) ? ((lane & 31) == 0) : (lane == 0);
    int rr0 = rbase + radd;
    const _Float16* cp = C + (size_t)rr0*M + co*8;
    float fArr[STEPS];
    #pragma unroll
    for (int s = 0; s < STEPS; s++) fArr[s] = fold[rr0 + rowst*s];
    half8 cb[4];
    #pragma unroll
    for (int s = 0; s < 3; s++) cb[s] = *(const half8*)(cp + (size_t)rowst*M*s);
    #pragma unroll
    for (int s = 0; s < STEPS; s++) {
        if (s + 3 < STEPS) cb[(s+3)&3] = *(const half8*)(cp + (size_t)rowst*M*(s+3));
        half8 cv = cb[s&3];
        float tv[8]; float mx = -3.4e38f;
        #pragma unroll
        for (int k = 0; k < 8; k++) {
            float t = h[k] - (float)cv[k]*inv_eps;
            tv[k] = t; mx = fmaxf(mx, t);
        }
        #pragma unroll
        for (int o = W; o; o >>= 1) mx = fmaxf(mx, __shfl_xor(mx, o));
        float ft;
        if (!hard) {
            float sum = 0.f;
            #pragma unroll
            for (int k = 0; k < 8; k++) sum += exp2f((tv[k] - mx)*LOG2E);
            #pragma unroll
            for (int o = W; o; o >>= 1) sum += __shfl_xor(sum, o);
            ft = -eps*(mx + LN2*__log2f(sum));
        } else {
            ft = -eps*mx;                         // |err| <= eps*ln(M), negligible
        }
        if (wr) {
            int row = rr0 + rowst*s;
            fout[row] = fin ? ft : 0.5f*(fArr[s] + ft);
        }
    }
}

// ---------------- fused pass: combine(prev partials) + row f + col partials -
// Launch k: (1) combine launch k-1's column partials -> g_k (LDS; slice-0
// block persists it for launch k+1), (2) single sweep of a 64-row slice:
// row-LSE -> f_{k+1}, online column-LSE partials (coalesced [sl*M+c] store).
// Cross-launch visibility comes from the dispatch boundary (no fences).
template<int M>
__device__ __forceinline__ void fused_pass(
    const _Float16* __restrict__ C,
    float* __restrict__ pm, float* __restrict__ ps,
    const float* __restrict__ gpo, float* __restrict__ gpn,
    const float* __restrict__ fpo, float* __restrict__ fpn,
    int q, float eps, float inv_eps, float loga, int hard, int fin,
    float prev_eps, int prev_hard, int first,
    float* s_g, float (*s_m)[512], float (*s_s)[512])
{
    const int NSL = (M == 256) ? 4 : 8;
    const int STEPS = (M == 256) ? 8 : 16;
    const int W = (M == 256) ? 16 : 32;
    int tid = threadIdx.x, lane = tid & 63, w = tid >> 6;
    // ---- phase 1: finalize g_k from previous launch's partials ----
    // (loads hoisted into independent arrays -> one latency round, coalesced)
    if (first) {
        for (int c = tid; c < M; c += 256) s_g[c] = 0.f;
    } else {
        for (int c = tid; c < M; c += 256) {
            float am[NSL], as[NSL];
            #pragma unroll
            for (int sl = 0; sl < NSL; sl++) am[sl] = pm[sl*M + c];
            if (!prev_hard) {
                #pragma unroll
                for (int sl = 0; sl < NSL; sl++) as[sl] = ps[sl*M + c];
            }
            float m = am[0];
            float s = prev_hard ? 0.f : as[0];
            #pragma unroll
            for (int sl = 1; sl < NSL; sl++) {
                if (!prev_hard) {
                    float mn = fmaxf(m, am[sl]);
                    s = s*exp2f(m - mn) + as[sl]*exp2f(am[sl] - mn);
                    m = mn;
                } else m = fmaxf(m, am[sl]);
            }
            float gt = prev_hard ? (-prev_eps*LN2*m)
                                 : (-prev_eps*LN2*(m + __log2f(s)));
            float gn = 0.5f*(gpo[c] + gt);
            s_g[c] = gn;
            if (q == 0) gpn[c] = gn;              // carry for next launch
        }
    }
    __syncthreads();
    // ---- phase 2: fused row+col sweep, 4-deep prefetch ----
    const float i2  = inv_eps * LOG2E;
    const float lg2 = loga * LOG2E;
    int co = (M == 256) ? (lane & 31) : lane;
    float h2[8];
    floatx4 h0 = *(const floatx4*)(s_g + co*8);
    floatx4 h1 = *(const floatx4*)(s_g + co*8 + 4);
    #pragma unroll
    for (int k = 0; k < 4; k++) { h2[k] = lg2 + h0[k]*i2; h2[4+k] = lg2 + h1[k]*i2; }
    int rbase = q*64 + w*16;
    int rowst = (M == 256) ? 2 : 1;
    int radd  = (M == 256) ? (lane >> 5) : 0;
    bool wr   = (M == 256) ? ((lane & 31) == 0) : (lane == 0);
    int rr0 = rbase + radd;
    const _Float16* cp = C + (size_t)rr0*M + co*8;
    float fArr[STEPS];
    #pragma unroll
    for (int s = 0; s < STEPS; s++) fArr[s] = fpo[rr0 + rowst*s];
    half8 cb[4];
    #pragma unroll
    for (int s = 0; s < 3; s++) cb[s] = *(const half8*)(cp + (size_t)rowst*M*s);
    float m2[8], ss[8];
    #pragma unroll
    for (int k = 0; k < 8; k++) { m2[k] = -3.4e38f; ss[k] = 0.f; }
    #pragma unroll
    for (int s = 0; s < STEPS; s++) {
        if (s + 3 < STEPS) cb[(s+3)&3] = *(const half8*)(cp + (size_t)rowst*M*(s+3));
        half8 cv = cb[s&3];
        float a2 = lg2 + fArr[s]*i2;
        float tv[8]; float mx = -3.4e38f;
        #pragma unroll
        for (int k = 0; k < 8; k++) {
            float d = (float)cv[k]*(-i2);         // shared: -C/eps in log2 units
            tv[k] = h2[k] + d; mx = fmaxf(mx, tv[k]);
            float u = a2 + d;                     // column contribution
            float mn = fmaxf(m2[k], u);
            if (!hard) ss[k] = ss[k]*exp2f(m2[k]-mn) + exp2f(u-mn);
            m2[k] = mn;
        }
        #pragma unroll
        for (int o = W; o; o >>= 1) mx = fmaxf(mx, __shfl_xor(mx, o));
        float ft;
        if (!hard) {
            float sum = 0.f;
            #pragma unroll
            for (int k = 0; k < 8; k++) sum += exp2f(tv[k] - mx);
            #pragma unroll
            for (int o = W; o; o >>= 1) sum += __shfl_xor(sum, o);
            ft = -eps*LN2*(mx + __log2f(sum));
        } else {
            ft = -eps*LN2*mx;
        }
        if (wr) fpn[rr0 + rowst*s] = fin ? ft : 0.5f*(fArr[s] + ft);
    }
    // ---- phase 3: merge col states across waves, store slice partial ------
    if (M == 256) {                               // halves share columns
        #pragma unroll
        for (int k = 0; k < 8; k++) {
            float mo = __shfl_xor(m2[k], 32), so = __shfl_xor(ss[k], 32);
            float mn = fmaxf(m2[k], mo);
            if (!hard) ss[k] = ss[k]*exp2f(m2[k]-mn) + so*exp2f(mo-mn);
            m2[k] = mn;
        }
        if (lane < 32) {
            #pragma unroll
            for (int k = 0; k < 8; k++) {
                s_m[w][lane*8+k] = m2[k];
                if (!hard) s_s[w][lane*8+k] = ss[k];
            }
        }
    } else {
        #pragma unroll
        for (int k = 0; k < 8; k++) {
            s_m[w][lane*8+k] = m2[k];
            if (!hard) s_s[w][lane*8+k] = ss[k];
        }
    }
    __syncthreads();
    for (int c = tid; c < M; c += 256) {
        float m = s_m[0][c];
        float s = hard ? 0.f : s_s[0][c];
        #pragma unroll
        for (int ww = 1; ww < 4; ww++) {
            float mo = s_m[ww][c];
            if (!hard) {
                float so = s_s[ww][c];
                float mn = fmaxf(m, mo);
                s = s*exp2f(m-mn) + so*exp2f(mo-mn);
                m = mn;
            } else m = fmaxf(m, mo);
        }
        pm[q*M + c] = m;                          // coalesced [sl*M+c]
        if (!hard) ps[q*M + c] = s;
    }
}

// ---------------- one eps-scaling iteration: 576 x 64-row blocks ------------
//  b <224 : global pair p=b>>3, slice q=b&7          (fused, 64 KB stream)
//  b <288 : global Cxx  c=(b-224)>>3, stripe (b-224)&7 (row-only)
//  b <512 : local pair p=(b-288)>>2, slice q=(b-288)&3 (fused, 32 KB stream)
//  else   : local Cxx  c=(b-512)>>2, stripe (b-512)&3  (row-only)
__global__ void __launch_bounds__(256) k_iter(float eps, float inv_eps, int par,
        int hard, int fin, int first, float prev_eps, int prev_hard) {
    const float LGA = -5.545177444479562f;        // -ln 256
    const float LGG = -6.238324625039508f;        // -ln 512
    __shared__ float s_g[512];
    __shared__ float s_m[4][512], s_s[4][512];
    int b = blockIdx.x, po = par, pn = par ^ 1;
    if (b < 224) {
        int p = b >> 3, q = b & 7;
        fused_pass<512>(g_CG + (size_t)p*262144,
            g_pm + 57344 + p*4096, g_ps + 57344 + p*4096,
            g_gG[po]+p*512, g_gG[pn]+p*512,
            g_fG[po]+p*512, g_fG[pn]+p*512,
            q, eps, inv_eps, LGG, hard, fin, prev_eps, prev_hard, first,
            s_g, s_m, s_s);
    } else if (b < 288) {
        int t = b - 224, c = t >> 3, q = t & 7;
        const float* h = g_pxG[po] + c*512;
        sm_pass<512>(g_CG + (size_t)(28+c)*262144, h, h, g_pxG[pn]+c*512, q*64,
                     eps, inv_eps, LGG, hard, fin);
    } else if (b < 512) {
        int t = b - 288, p = t >> 2, q = t & 3;
        fused_pass<256>(g_CL + (size_t)p*65536,
            g_pm + p*1024, g_ps + p*1024,
            g_gL[po]+p*256, g_gL[pn]+p*256,
            g_fL[po]+p*256, g_fL[pn]+p*256,
            q, eps, inv_eps, LGA, hard, fin, prev_eps, prev_hard, first,
            s_g, s_m, s_s);
    } else {
        int t = b - 512, c = t >> 2, q = t & 3;
        const float* h = g_pxL[po] + c*256;
        sm_pass<256>(g_CL + (size_t)(56+c)*65536, h, h, g_pxL[pn]+c*256, q*64,
                     eps, inv_eps, LGA, hard, fin);
    }
}

// ---------------- finalize g_fin from the fin launch's partials -------------
__global__ void k_fin(float eps_f) {
    int b = blockIdx.x, tid = threadIdx.x;        // 84 blocks x 256
    if (b < 28) {                                 // global pairs (NSL=8, M=512)
        const float* pm = g_pm + 57344 + b*4096;
        for (int c = tid; c < 512; c += 256) {
            float m = pm[c];
            #pragma unroll
            for (int sl = 1; sl < 8; sl++) m = fmaxf(m, pm[sl*512 + c]);
            g_gG[1][b*512 + c] = -eps_f*LN2*m;
        }
    } else {                                      // local pairs (NSL=4, M=256)
        int p = b - 28;
        const float* pm = g_pm + p*1024;
        int c = tid;
        float m = fmaxf(fmaxf(pm[c], pm[256+c]), fmaxf(pm[512+c], pm[768+c]));
        g_gL[1][p*256 + c] = -eps_f*LN2*m;
    }
}

// ---------------- final reduction to the scalar loss ------------------------
__global__ void k_combine(float* __restrict__ out) {
    __shared__ float red[4][4];
    int tid = threadIdx.x;                        // 256 threads
    float sfg_l = 0.f, spx_l = 0.f, sfg_g = 0.f, spx_g = 0.f;
    for (int i = tid; i < 14336; i += 256) sfg_l += g_fL[1][i] + g_gL[1][i];
    for (int i = tid; i < 4096;  i += 256) spx_l += g_pxL[1][i];
    for (int i = tid; i < 14336; i += 256) sfg_g += g_fG[1][i] + g_gG[1][i];
    for (int i = tid; i < 4096;  i += 256) spx_g += g_pxG[1][i];
    for (int o = 32; o; o >>= 1) {
        sfg_l += __shfl_xor(sfg_l, o); spx_l += __shfl_xor(spx_l, o);
        sfg_g += __shfl_xor(sfg_g, o); spx_g += __shfl_xor(spx_g, o);
    }
    int w = tid >> 6;
    if ((tid & 63) == 0) { red[0][w] = sfg_l; red[1][w] = spx_l; red[2][w] = sfg_g; red[3][w] = spx_g; }
    __syncthreads();
    if (tid == 0) {
        float SL = red[0][0]+red[0][1]+red[0][2]+red[0][3];
        float PL = red[1][0]+red[1][1]+red[1][2]+red[1][3];
        float SG = red[2][0]+red[2][1]+red[2][2]+red[2][3];
        float PG = red[3][0]+red[3][1]+red[3][2]+red[3][3];
        float local_l  = SL/14336.f - PL/2048.f;
        float global_l = SG/14336.f - PG/2048.f;
        out[0] = 1.0f*local_l + 0.5f*global_l;
    }
}

// ---------------- host launcher ---------------------------------------------
extern "C" void kernel_launch(void* const* d_in, const int* in_sizes, int n_in,
                              void* d_out, int out_size, void* d_ws, size_t ws_size,
                              hipStream_t stream) {
    (void)in_sizes; (void)n_in; (void)out_size; (void)d_ws; (void)ws_size;
    const float* feat  = (const float*)d_in[0];
    const int* labels  = (const int*)d_in[1];
    const int* subg    = (const int*)d_in[2];

    k_index <<<24,    64, 0, stream>>>(labels, subg);
    k_gather<<<2048, 256, 0, stream>>>(feat);
    k_gemm  <<<13824,256, 0, stream>>>();
    k_init  <<<374,  256, 0, stream>>>();

    // eps schedule identical to reference (double, like numpy)
    double eps0 = 4.0*256.0, ratio = 0.9*0.9, target = 1e-4*1e-4;
    int n = (int)ceil(log(target/eps0)/log(ratio));    // 121 -> 122 iterations
    float ef = 1e-8f;
    float prev_ef = 0.f; int prev_hard = 0;
    for (int k = 0; k <= n; k++) {
        double e = eps0 * pow(ratio, (double)k);
        if (e < target) e = target;
        ef = (float)e;
        int hard = (ef < 1e-5f) ? 1 : 0;
        k_iter<<<576, 256, 0, stream>>>(ef, (float)(1.0/(double)ef), k & 1,
                                        hard, 0, (k == 0) ? 1 : 0, prev_ef, prev_hard);
        prev_ef = ef; prev_hard = hard;
    }
    // final extrapolation at eps_f: combine(partials_121)->g_122, raw f/px,
    // col partials with f_122; then k_fin combines them into g_fin.
    k_iter<<<576, 256, 0, stream>>>(ef, (float)(1.0/(double)ef), 0,
                                    1, 1, 0, prev_ef, prev_hard);
    k_fin<<<84, 256, 0, stream>>>(ef);
    k_combine<<<1, 256, 0, stream>>>((float*)d_out);
}

// Round 6
// 2004.316 us; speedup vs baseline: 2.9893x; 1.9254x over previous
//
#include <hip/hip_runtime.h>
#include <math.h>

#define LOG2E 1.4426950408889634f
#define LN2   0.6931471805599453f

typedef short    short8  __attribute__((ext_vector_type(8)));
typedef float    floatx4 __attribute__((ext_vector_type(4)));
typedef _Float16 half8   __attribute__((ext_vector_type(8)));

__constant__ int c_pi[28] = {0,0,0,0,0,0,0,1,1,1,1,1,1,2,2,2,2,2,3,3,3,3,4,4,4,5,5,6};
__constant__ int c_pj[28] = {1,2,3,4,5,6,7,2,3,4,5,6,7,3,4,5,6,7,4,5,6,7,5,6,7,6,7,7};

// ---------------- static device storage ----------------
__device__ unsigned short g_cellsL[16*256*256];   // bf16 bits, gathered local cells
__device__ unsigned short g_cellsG[8*512*256];    // bf16 bits, gathered global cells
__device__ float g_x2L[16*256];
__device__ float g_x2G[8*512];
__device__ int   g_idxL[16*256];
__device__ int   g_idxG[8*512];
// fp16 cost matrices. Local: [0,56)=Cxy, [56,112)=Cyx(T), [112,128)=Cxx. 16.8 MB
__device__ _Float16 g_CL[128*256*256];
// Global: [0,28)=Cxy, [28,56)=Cyx(T), [56,64)=Cxx. 33.6 MB
__device__ _Float16 g_CG[64*512*512];
__device__ float g_fL[2][56*256];
__device__ float g_gL[2][56*256];
__device__ float g_pxL[2][16*256];
__device__ float g_fG[2][28*512];
__device__ float g_gG[2][28*512];
__device__ float g_pxG[2][8*512];

// ---------------- helpers ----------------
__device__ __forceinline__ unsigned short f2bf(float f) {
    unsigned u = __float_as_uint(f);
    u += 0x7fffu + ((u >> 16) & 1u);          // RNE; inputs are finite
    return (unsigned short)(u >> 16);
}

// ---------------- index lists: first-m matches in order (ballot scan) -------
__global__ void k_index(const int* __restrict__ labels, const int* __restrict__ subg) {
    int b = blockIdx.x, lane = threadIdx.x;   // 24 blocks x 64 threads
    int want_l, want_s, cap; int* out;
    if (b < 16) { want_l = b >> 3; want_s = b & 7; cap = 256; out = g_idxL + b*256; }
    else        { want_l = -1;     want_s = b - 16; cap = 512; out = g_idxG + (b-16)*512; }
    int cnt = 0;
    for (int base = 0; base < 4096; base += 64) {
        int i = base + lane;
        bool m = (subg[i] == want_s) && (want_l < 0 || labels[i] == want_l);
        unsigned long long mask = __ballot(m);
        int pos = cnt + __popcll(mask & ((1ull << lane) - 1ull));
        if (m && pos < cap) out[pos] = i;
        cnt += __popcll(mask);
    }
}

// ---------------- gather rows -> bf16 cells + fp32 sq-norms -----------------
__global__ void k_gather(const float* __restrict__ feat) {
    int wv = blockIdx.x*4 + (threadIdx.x >> 6);   // 8192 waves, one row each
    int lane = threadIdx.x & 63;
    const float* src; unsigned short* dst; float* x2out;
    if (wv < 4096) {
        int c = wv >> 8, row = wv & 255;
        src = feat + (size_t)g_idxL[c*256+row]*256;
        dst = g_cellsL + (size_t)(c*256+row)*256;
        x2out = g_x2L + c*256 + row;
    } else {
        int v = wv - 4096; int c = v >> 9, row = v & 511;
        src = feat + (size_t)g_idxG[c*512+row]*256;
        dst = g_cellsG + (size_t)(c*512+row)*256;
        x2out = g_x2G + c*512 + row;
    }
    floatx4 v4 = *(const floatx4*)(src + lane*4);
    float s = v4[0]*v4[0] + v4[1]*v4[1] + v4[2]*v4[2] + v4[3]*v4[3];
    unsigned lo = (unsigned)f2bf(v4[0]) | ((unsigned)f2bf(v4[1]) << 16);
    unsigned hi = (unsigned)f2bf(v4[2]) | ((unsigned)f2bf(v4[3]) << 16);
    unsigned* d32 = (unsigned*)dst;
    d32[lane*2] = lo; d32[lane*2+1] = hi;
    for (int o = 32; o; o >>= 1) s += __shfl_xor(s, o);
    if (lane == 0) *x2out = s;
}

// ---------------- cost matrices via bf16 MFMA (wave = one 16x16 tile) -------
// C_ij = 0.5*max(x2_i + y2_j - 2*x.y, 0), stored fp16. T matrices are built as
// an independent GEMM with A/B swapped (coalesced writes, no transpose pass).
__global__ void k_gemm() {
    int job = blockIdx.x*4 + (threadIdx.x >> 6);
    int lane = threadIdx.x & 63;
    const unsigned short *A, *B; _Float16* Cout; const float *x2a, *x2b;
    int m, ti, tj;
    if (job < 32768) {                      // local: 128 matrices x 256 tiles
        int mm = job >> 8, t = job & 255; ti = t >> 4; tj = t & 15; m = 256;
        int ca, cb;
        if (mm < 56)       { int lbl = mm/28,  q = mm%28;  ca = lbl*8 + c_pi[q]; cb = lbl*8 + c_pj[q]; }
        else if (mm < 112) { int p = mm-56; int lbl = p/28, q = p%28;
                             ca = lbl*8 + c_pj[q]; cb = lbl*8 + c_pi[q]; }
        else               { int c = mm-112; ca = cb = c; }
        A = g_cellsL + (size_t)ca*65536; B = g_cellsL + (size_t)cb*65536;
        x2a = g_x2L + ca*256; x2b = g_x2L + cb*256;
        Cout = g_CL + (size_t)mm*65536;
    } else {                                // global: 64 matrices x 1024 tiles
        int jj = job - 32768; int mm = jj >> 10, t = jj & 1023; ti = t >> 5; tj = t & 31; m = 512;
        int ca, cb;
        if (mm < 28)      { ca = c_pi[mm];    cb = c_pj[mm]; }
        else if (mm < 56) { ca = c_pj[mm-28]; cb = c_pi[mm-28]; }
        else              { ca = cb = mm-56; }
        A = g_cellsG + (size_t)ca*131072; B = g_cellsG + (size_t)cb*131072;
        x2a = g_x2G + ca*512; x2b = g_x2G + cb*512;
        Cout = g_CG + (size_t)mm*262144;
    }
    int r = lane & 15, quad = lane >> 4;
    const unsigned short* Ap = A + (size_t)(ti*16 + r)*256 + quad*8;
    const unsigned short* Bp = B + (size_t)(tj*16 + r)*256 + quad*8;
    floatx4 acc = {0.f, 0.f, 0.f, 0.f};
    #pragma unroll
    for (int k = 0; k < 256; k += 32) {
        short8 av = *(const short8*)(Ap + k);
        short8 bv = *(const short8*)(Bp + k);
        acc = __builtin_amdgcn_mfma_f32_16x16x32_bf16(av, bv, acc, 0, 0, 0);
    }
    int jc = tj*16 + r;                     // D: col = lane&15, row = quad*4 + reg
    float y2 = x2b[jc];
    #pragma unroll
    for (int rr = 0; rr < 4; rr++) {
        int ir = ti*16 + quad*4 + rr;
        float v = x2a[ir] + y2 - 2.f*acc[rr];
        Cout[(size_t)ir*m + jc] = (_Float16)(0.5f*fmaxf(v, 0.f));
    }
}

// ---------------- zero the parity-0 potential buffers -----------------------
__global__ void k_init() {
    int t = blockIdx.x*256 + threadIdx.x;   // 65536 threads
    if      (t < 14336) g_fL[0][t] = 0.f;
    else if (t < 28672) g_gL[0][t-14336] = 0.f;
    else if (t < 32768) g_pxL[0][t-28672] = 0.f;
    else if (t < 47104) g_fG[0][t-32768] = 0.f;
    else if (t < 61440) g_gG[0][t-47104] = 0.f;
    else                g_pxG[0][t-61440] = 0.f;
}

// ---------------- row softmin pass, fully register-resident -----------------
// ft_i = -eps*LSE_j(h_j - C_ij/eps); every pass is a row pass (T materialized).
// M=256: half-wave per row (lanes 0-31 / 32-63), 2*STEPS rows/wave.
// M=512: full wave per row, STEPS rows/wave.
// STEPS=6 main stripes (6 KB/wave), STEPS=2 tail stripes (2 KB/wave).
template<int M, int STEPS>
__device__ __forceinline__ void sm_pass(const _Float16* __restrict__ C,
    const float* __restrict__ hsrc, const float* __restrict__ fold,
    float* __restrict__ fout, int r0, float eps, float inv_eps, float loga,
    int hard, int fin)
{
    const int W = (M == 256) ? 16 : 32;     // shfl butterfly start
    int tid = threadIdx.x, lane = tid & 63, w = tid >> 6;
    int co = (M == 256) ? (lane & 31) : lane;
    float h[8];
    floatx4 h0 = *(const floatx4*)(hsrc + co*8);
    floatx4 h1 = *(const floatx4*)(hsrc + co*8 + 4);
    #pragma unroll
    for (int k = 0; k < 4; k++) { h[k] = loga + h0[k]*inv_eps; h[4+k] = loga + h1[k]*inv_eps; }
    int rbase = (M == 256) ? (r0 + w*2*STEPS) : (r0 + w*STEPS);
    int rowst = (M == 256) ? 2 : 1;
    int radd  = (M == 256) ? (lane >> 5) : 0;
    bool wr   = (M == 256) ? ((lane & 31) == 0) : (lane == 0);

    const _Float16* cp = C + (size_t)(rbase + radd)*M + co*8;
    half8 cv = *(const half8*)cp;           // 2-stage pipeline: prefetch next row
    #pragma unroll
    for (int s = 0; s < STEPS; s++) {
        half8 cvn = cv;
        if (s < STEPS-1) cvn = *(const half8*)(cp + (size_t)rowst*M);
        float tv[8]; float mx = -3.4e38f;
        #pragma unroll
        for (int k = 0; k < 8; k++) {
            float t = h[k] - (float)cv[k]*inv_eps;
            tv[k] = t; mx = fmaxf(mx, t);
        }
        #pragma unroll
        for (int o = W; o; o >>= 1) mx = fmaxf(mx, __shfl_xor(mx, o));
        float ft;
        if (!hard) {
            float sum = 0.f;
            #pragma unroll
            for (int k = 0; k < 8; k++) sum += exp2f((tv[k] - mx)*LOG2E);
            #pragma unroll
            for (int o = W; o; o >>= 1) sum += __shfl_xor(sum, o);
            ft = -eps*(mx + LN2*__log2f(sum));
        } else {
            ft = -eps*mx;                   // |err| <= eps*ln(M), negligible for eps<1e-5
        }
        if (wr) {
            int row = rbase + rowst*s + radd;
            fout[row] = fin ? ft : 0.5f*(fold[row] + ft);
        }
        cv = cvn; cp += (size_t)rowst*M;
    }
}

// ---------------- one eps-scaling iteration -------------------------------
// 2176 blocks, 8704 waves (7936 main @6KB + 768 tail @2KB), tails first so
// the 128 deferred blocks backfill behind them (cap = 8192 resident waves).
//  b <   64 : global tail   : matrix m=b,        rows [504,512), STEPS=2
//  b <  192 : local  tail   : matrix m=b-64,     rows [240,256), STEPS=2
//  b < 1536 : global main   : m=(b-192)/21, stripe r0=((b-192)%21)*24, STEPS=6
//  else     : local  main   : m=(b-1536)/5, stripe r0=((b-1536)%5)*48, STEPS=6
__global__ void __launch_bounds__(256) k_iter(float eps, float inv_eps, int par,
                                              int hard, int fin) {
    const float LGA = -5.545177444479562f;  // -ln 256
    const float LGG = -6.238324625039508f;  // -ln 512
    int b = blockIdx.x;
    int po = par, pn = par ^ 1;
    bool isG, tail; int m, r0;
    if (b < 64)        { isG = true;  tail = true;  m = b;        r0 = 504; }
    else if (b < 192)  { isG = false; tail = true;  m = b - 64;   r0 = 240; }
    else if (b < 1536) { int t = b - 192;  isG = true;  tail = false; m = t/21; r0 = (t%21)*24; }
    else               { int t = b - 1536; isG = false; tail = false; m = t/5;  r0 = (t%5)*48; }
    if (isG) {
        const _Float16* C = g_CG + (size_t)m*262144;
        const float *h, *fo; float* fn;
        if (m < 28)      { h = g_gG[po]+m*512;  fo = g_fG[po]+m*512;  fn = g_fG[pn]+m*512; }
        else if (m < 56) { int p = m-28;  h = g_fG[po]+p*512;  fo = g_gG[po]+p*512;  fn = g_gG[pn]+p*512; }
        else             { int c = m-56;  h = g_pxG[po]+c*512; fo = h;               fn = g_pxG[pn]+c*512; }
        if (tail) sm_pass<512,2>(C, h, fo, fn, r0, eps, inv_eps, LGG, hard, fin);
        else      sm_pass<512,6>(C, h, fo, fn, r0, eps, inv_eps, LGG, hard, fin);
    } else {
        const _Float16* C = g_CL + (size_t)m*65536;
        const float *h, *fo; float* fn;
        if (m < 56)       { h = g_gL[po]+m*256;  fo = g_fL[po]+m*256;  fn = g_fL[pn]+m*256; }
        else if (m < 112) { int p = m-56;  h = g_fL[po]+p*256;  fo = g_gL[po]+p*256;  fn = g_gL[pn]+p*256; }
        else              { int c = m-112; h = g_pxL[po]+c*256; fo = h;               fn = g_pxL[pn]+c*256; }
        if (tail) sm_pass<256,2>(C, h, fo, fn, r0, eps, inv_eps, LGA, hard, fin);
        else      sm_pass<256,6>(C, h, fo, fn, r0, eps, inv_eps, LGA, hard, fin);
    }
}

// ---------------- final reduction to the scalar loss ------------------------
__global__ void k_combine(float* __restrict__ out) {
    __shared__ float red[4][4];
    int tid = threadIdx.x;                  // 256 threads
    float sfg_l = 0.f, spx_l = 0.f, sfg_g = 0.f, spx_g = 0.f;
    for (int i = tid; i < 14336; i += 256) sfg_l += g_fL[1][i] + g_gL[1][i];
    for (int i = tid; i < 4096;  i += 256) spx_l += g_pxL[1][i];
    for (int i = tid; i < 14336; i += 256) sfg_g += g_fG[1][i] + g_gG[1][i];
    for (int i = tid; i < 4096;  i += 256) spx_g += g_pxG[1][i];
    for (int o = 32; o; o >>= 1) {
        sfg_l += __shfl_xor(sfg_l, o); spx_l += __shfl_xor(spx_l, o);
        sfg_g += __shfl_xor(sfg_g, o); spx_g += __shfl_xor(spx_g, o);
    }
    int w = tid >> 6;
    if ((tid & 63) == 0) { red[0][w] = sfg_l; red[1][w] = spx_l; red[2][w] = sfg_g; red[3][w] = spx_g; }
    __syncthreads();
    if (tid == 0) {
        float SL = red[0][0]+red[0][1]+red[0][2]+red[0][3];
        float PL = red[1][0]+red[1][1]+red[1][2]+red[1][3];
        float SG = red[2][0]+red[2][1]+red[2][2]+red[2][3];
        float PG = red[3][0]+red[3][1]+red[3][2]+red[3][3];
        float local_l  = SL/14336.f - PL/2048.f;
        float global_l = SG/14336.f - PG/2048.f;
        out[0] = 1.0f*local_l + 0.5f*global_l;
    }
}

// ---------------- host launcher ---------------------------------------------
extern "C" void kernel_launch(void* const* d_in, const int* in_sizes, int n_in,
                              void* d_out, int out_size, void* d_ws, size_t ws_size,
                              hipStream_t stream) {
    (void)in_sizes; (void)n_in; (void)out_size; (void)d_ws; (void)ws_size;
    const float* feat  = (const float*)d_in[0];
    const int* labels  = (const int*)d_in[1];
    const int* subg    = (const int*)d_in[2];

    k_index <<<24,    64, 0, stream>>>(labels, subg);
    k_gather<<<2048, 256, 0, stream>>>(feat);
    k_gemm  <<<24576,256, 0, stream>>>();
    k_init  <<<256,  256, 0, stream>>>();

    // eps schedule identical to reference (double, like numpy)
    double eps0 = 4.0*256.0, ratio = 0.9*0.9, target = 1e-4*1e-4;
    int n = (int)ceil(log(target/eps0)/log(ratio));    // 121 -> 122 iterations
    float ef = 1e-8f;
    for (int k = 0; k <= n; k++) {
        double e = eps0 * pow(ratio, (double)k);
        if (e < target) e = target;
        ef = (float)e;
        int hard = (ef < 1e-5f) ? 1 : 0;
        k_iter<<<2176, 256, 0, stream>>>(ef, (float)(1.0/(double)ef), k & 1, hard, 0);
    }
    // final extrapolation at eps_f (reads parity 0 carry, writes raw to parity 1)
    k_iter<<<2176, 256, 0, stream>>>(ef, (float)(1.0/(double)ef), 0, 1, 1);
    k_combine<<<1, 256, 0, stream>>>((float*)d_out);
}